// Round 13
// baseline (547.292 us; speedup 1.0000x reference)
//
#include <hip/hip_runtime.h>

#define HID 128
#define INP 64
#define LN_EPS 1e-5f
#define RT 64   // rows per block in GEMM kernels

typedef __attribute__((ext_vector_type(8))) short bf16x8;
typedef __attribute__((ext_vector_type(4))) float f32x4;

__device__ __forceinline__ unsigned f2bf(float f) {
    unsigned u = __float_as_uint(f);
    return (u + 0x7FFFu + ((u >> 16) & 1u)) >> 16;   // RNE
}
__device__ __forceinline__ float bflo(unsigned v) { return __uint_as_float(v << 16); }
__device__ __forceinline__ float bfhi(unsigned v) { return __uint_as_float(v & 0xFFFF0000u); }

// ---------------- CSR count (16 edges/thread, records per-edge rank) + fused weight prep ----------------
__global__ __launch_bounds__(256) void k_count(const int* __restrict__ dst, int nE, int* __restrict__ cnt,
                                               int* __restrict__ rank, int nEdgeThreads,
                                               const float* __restrict__ W_in, const float* __restrict__ W_l,
                                               unsigned short* __restrict__ Wt_in, unsigned short* __restrict__ Wt_l) {
    int t = blockIdx.x * 256 + threadIdx.x;
    if (t < nEdgeThreads) {
        int base = t * 16;
        if (base + 16 <= nE) {
            int4 d[4];
#pragma unroll
            for (int j = 0; j < 4; ++j) d[j] = *reinterpret_cast<const int4*>(dst + base + j * 4);
            int p[16];
#pragma unroll
            for (int j = 0; j < 4; ++j) {
                p[j * 4 + 0] = atomicAdd(&cnt[d[j].x], 1);
                p[j * 4 + 1] = atomicAdd(&cnt[d[j].y], 1);
                p[j * 4 + 2] = atomicAdd(&cnt[d[j].z], 1);
                p[j * 4 + 3] = atomicAdd(&cnt[d[j].w], 1);
            }
#pragma unroll
            for (int j = 0; j < 4; ++j)
                *reinterpret_cast<int4*>(rank + base + j * 4) =
                    make_int4(p[j * 4 + 0], p[j * 4 + 1], p[j * 4 + 2], p[j * 4 + 3]);
        } else {
            for (int e = base; e < nE; ++e) rank[e] = atomicAdd(&cnt[dst[e]], 1);
        }
        return;
    }
    int i = t - nEdgeThreads;
    if (i < 128 * 64) {
        int col = i >> 6, k = i & 63;
        Wt_in[i] = (unsigned short)f2bf(W_in[(size_t)k * HID + col]);
    } else if (i < 128 * 64 + 3 * 128 * 128) {
        int j = i - 128 * 64;
        int l = j >> 14, r = j & 16383;
        int col = r >> 7, k = r & 127;
        Wt_l[j] = (unsigned short)f2bf(W_l[(size_t)l * 16384 + (size_t)k * HID + col]);
    }
}

__global__ void k_scan1(const int* __restrict__ cnt, int n, int* __restrict__ rowp, int* __restrict__ bsum) {
    __shared__ int s[256];
    int i = blockIdx.x * 256 + threadIdx.x;
    int v = (i < n) ? cnt[i] : 0;
    s[threadIdx.x] = v;
    __syncthreads();
    for (int off = 1; off < 256; off <<= 1) {
        int t = (threadIdx.x >= off) ? s[threadIdx.x - off] : 0;
        __syncthreads();
        s[threadIdx.x] += t;
        __syncthreads();
    }
    if (i < n) rowp[i] = s[threadIdx.x] - v;  // exclusive (within block)
    if (threadIdx.x == 255) bsum[blockIdx.x] = s[255];
}

// scan3 with inline redundant scan of bsum (replaces scan2)
__global__ void k_scan3(int* __restrict__ rowp, const int* __restrict__ bsum, const int* __restrict__ cnt,
                        int n, int nE, float* __restrict__ invd, int nb) {
    __shared__ int s[256];
    __shared__ int boff;
    int v = (threadIdx.x < nb) ? bsum[threadIdx.x] : 0;
    s[threadIdx.x] = v;
    __syncthreads();
    for (int off = 1; off < 256; off <<= 1) {
        int t = (threadIdx.x >= off) ? s[threadIdx.x - off] : 0;
        __syncthreads();
        s[threadIdx.x] += t;
        __syncthreads();
    }
    if (threadIdx.x == blockIdx.x) boff = s[threadIdx.x] - v;  // exclusive prefix for this block
    __syncthreads();
    int i = blockIdx.x * 256 + threadIdx.x;
    if (i < n) {
        rowp[i] += boff;
        int c = cnt[i];
        invd[i] = 1.0f / (float)(c > 1 ? c : 1);
    } else if (i == n) {
        rowp[n] = nE;
    }
}

// ---------------- fused: [0,tgrid) in-projection MFMA; [tgrid,..) atomic-free CSR fill ----------------
__global__ __launch_bounds__(256) void k_fillproj(const float* __restrict__ x,
                                                  const unsigned short* __restrict__ Wt,  // [128][64] bf16
                                                  const float* __restrict__ b,
                                                  unsigned* __restrict__ hout, int n, int tgrid,
                                                  const int* __restrict__ src, const int* __restrict__ dst,
                                                  const int* __restrict__ rank, const int* __restrict__ rowp,
                                                  int nE, int* __restrict__ csrc) {
    const int tid = threadIdx.x;
    if (blockIdx.x >= tgrid) {
        int t = (blockIdx.x - tgrid) * 256 + tid;
        int base = t * 16;
        if (base + 16 <= nE) {
            int4 d[4], s[4], r[4];
#pragma unroll
            for (int j = 0; j < 4; ++j) {
                d[j] = *reinterpret_cast<const int4*>(dst + base + j * 4);
                s[j] = *reinterpret_cast<const int4*>(src + base + j * 4);
                r[j] = *reinterpret_cast<const int4*>(rank + base + j * 4);
            }
#pragma unroll
            for (int j = 0; j < 4; ++j) {
                __builtin_nontemporal_store(s[j].x, &csrc[rowp[d[j].x] + r[j].x]);
                __builtin_nontemporal_store(s[j].y, &csrc[rowp[d[j].y] + r[j].y]);
                __builtin_nontemporal_store(s[j].z, &csrc[rowp[d[j].z] + r[j].z]);
                __builtin_nontemporal_store(s[j].w, &csrc[rowp[d[j].w] + r[j].w]);
            }
        } else if (base < nE) {
            for (int e = base; e < nE; ++e)
                __builtin_nontemporal_store(src[e], &csrc[rowp[dst[e]] + rank[e]]);
        }
        return;
    }
    __shared__ unsigned short xs[RT * INP];  // 8 KB, swizzled
    const int row0 = blockIdx.x * RT;
#pragma unroll
    for (int j = 0; j < 2; ++j) {
        int fid = tid + j * 256;
        int r = fid >> 3, c = fid & 7;
        int grow = row0 + r;
        unsigned o[4] = {0, 0, 0, 0};
        if (grow < n) {
            float4 v0 = *reinterpret_cast<const float4*>(x + (size_t)grow * INP + c * 8);
            float4 v1 = *reinterpret_cast<const float4*>(x + (size_t)grow * INP + c * 8 + 4);
            o[0] = f2bf(v0.x) | (f2bf(v0.y) << 16);
            o[1] = f2bf(v0.z) | (f2bf(v0.w) << 16);
            o[2] = f2bf(v1.x) | (f2bf(v1.y) << 16);
            o[3] = f2bf(v1.z) | (f2bf(v1.w) << 16);
        }
        int sw = c ^ (r & 7);
        *reinterpret_cast<uint4*>(xs + r * INP + sw * 8) = make_uint4(o[0], o[1], o[2], o[3]);
    }
    __syncthreads();

    const int l = tid & 63;
    const int w = tid >> 6;
    const int l15 = l & 15, lg = l >> 4;
    const int xrow = w * 16 + l15;

    f32x4 acc[8];
#pragma unroll
    for (int t = 0; t < 8; ++t) acc[t] = (f32x4){0.f, 0.f, 0.f, 0.f};

#pragma unroll
    for (int kc = 0; kc < 2; ++kc) {
        int bc = (kc * 4 + lg) ^ (xrow & 7);
        bf16x8 bfrag = *reinterpret_cast<const bf16x8*>(xs + xrow * INP + bc * 8);
        const unsigned short* wp = Wt + (size_t)l15 * INP + kc * 32 + lg * 8;
        bf16x8 af[8];
#pragma unroll
        for (int t = 0; t < 8; ++t) af[t] = *reinterpret_cast<const bf16x8*>(wp + (size_t)t * 16 * INP);
#pragma unroll
        for (int t = 0; t < 8; ++t)
            acc[t] = __builtin_amdgcn_mfma_f32_16x16x32_bf16(af[t], bfrag, acc[t], 0, 0, 0);
    }

    int grow = row0 + xrow;
    if (grow < n) {
#pragma unroll
        for (int t = 0; t < 8; ++t) {
            int c0 = t * 16 + lg * 4;
            f32x4 bb = *reinterpret_cast<const f32x4*>(b + c0);
            f32x4 o = acc[t] + bb;
            uint2 p;
            p.x = f2bf(o.x) | (f2bf(o.y) << 16);
            p.y = f2bf(o.z) | (f2bf(o.w) << 16);
            *reinterpret_cast<uint2*>(hout + (size_t)grow * 64 + t * 8 + lg * 2) = p;
        }
    }
}

// ---------------- persistent network kernel with manual device-scope barrier ----------------
// bar layout (ints, all zeroed each launch): [sub*32] 8 arrival sub-counters;
// [256] master count; [512 + sub*32] epoch broadcast lines.
__global__ __launch_bounds__(256, 3) void k_net(unsigned* __restrict__ hbA, unsigned* __restrict__ hbB,
                                                unsigned* __restrict__ aggx,
                                                const int* __restrict__ rowp, const int* __restrict__ csrc,
                                                const float* __restrict__ invd,
                                                const unsigned short* __restrict__ Wt_all,
                                                const float* __restrict__ b_all, const float* __restrict__ g_all,
                                                const float* __restrict__ lnb_all,
                                                const int* __restrict__ n_act_p, float* __restrict__ accum,
                                                const float* __restrict__ W_o, const float* __restrict__ b_o,
                                                float* __restrict__ out, int n, int tgrid,
                                                int* __restrict__ bar) {
    const int tid = threadIdx.x;
    const int lane = tid & 63;
    const int w = tid >> 6;
    const int nWaves = gridDim.x * 4;
    const int waveId = blockIdx.x * 4 + w;
    const int l15 = lane & 15, lg = lane >> 4;

    int epoch = 0;
    auto gbar = [&]() {
        __syncthreads();
        if (tid == 0) {
            const int sub = blockIdx.x & 7;
            const int subCount = gridDim.x >> 3;   // gridDim.x % 8 == 0
            __threadfence();
            if (atomicAdd(&bar[sub * 32], 1) == subCount - 1) {
                atomicExch(&bar[sub * 32], 0);
                if (atomicAdd(&bar[256], 1) == 7) {
                    atomicExch(&bar[256], 0);
                    __threadfence();
#pragma unroll
                    for (int i = 0; i < 8; ++i) atomicExch(&bar[512 + i * 32], epoch + 1);
                }
            }
            while (atomicAdd(&bar[512 + sub * 32], 0) <= epoch) __builtin_amdgcn_s_sleep(8);
            __threadfence();
        }
        __syncthreads();
        ++epoch;
    };

    const unsigned* hin = hbA;
    unsigned* hout = hbB;

    for (int l = 0; l < 3; ++l) {
        // ======== agg phase: grid-stride over nodes, one wave per node ========
        {
            const int grp = lane >> 4, cidx = lane & 15;
            const uint4* hb4 = reinterpret_cast<const uint4*>(hin);
            for (int node = waveId; node < n; node += nWaves) {
                int e0 = rowp[node], e1 = rowp[node + 1];
                int deg = e1 - e0;
                float a0 = 0, a1 = 0, a2 = 0, a3 = 0, a4 = 0, a5 = 0, a6 = 0, a7 = 0;
                for (int base = 0; base < deg; base += 64) {
                    int m = deg - base;
                    if (m > 64) m = 64;
                    int myidx = (base + lane < deg) ? csrc[e0 + base + lane] : 0;
                    int steps = (m + 3) >> 2;
                    int jj = 0;
                    for (; jj + 4 <= steps; jj += 4) {
                        uint4 v[4];
#pragma unroll
                        for (int k = 0; k < 4; ++k) {
                            int ei = (jj + k) * 4 + grp;
                            int s = __shfl(myidx, ei);
                            v[k] = (ei < m) ? hb4[(size_t)s * 16 + cidx] : make_uint4(0, 0, 0, 0);
                        }
#pragma unroll
                        for (int k = 0; k < 4; ++k) {
                            a0 += bflo(v[k].x); a1 += bfhi(v[k].x);
                            a2 += bflo(v[k].y); a3 += bfhi(v[k].y);
                            a4 += bflo(v[k].z); a5 += bfhi(v[k].z);
                            a6 += bflo(v[k].w); a7 += bfhi(v[k].w);
                        }
                    }
                    for (; jj < steps; ++jj) {
                        int ei = jj * 4 + grp;
                        int s = __shfl(myidx, ei);
                        if (ei < m) {
                            uint4 v = hb4[(size_t)s * 16 + cidx];
                            a0 += bflo(v.x); a1 += bfhi(v.x);
                            a2 += bflo(v.y); a3 += bfhi(v.y);
                            a4 += bflo(v.z); a5 += bfhi(v.z);
                            a6 += bflo(v.w); a7 += bfhi(v.w);
                        }
                    }
                }
                a0 += __shfl_xor(a0, 16, 64); a0 += __shfl_xor(a0, 32, 64);
                a1 += __shfl_xor(a1, 16, 64); a1 += __shfl_xor(a1, 32, 64);
                a2 += __shfl_xor(a2, 16, 64); a2 += __shfl_xor(a2, 32, 64);
                a3 += __shfl_xor(a3, 16, 64); a3 += __shfl_xor(a3, 32, 64);
                a4 += __shfl_xor(a4, 16, 64); a4 += __shfl_xor(a4, 32, 64);
                a5 += __shfl_xor(a5, 16, 64); a5 += __shfl_xor(a5, 32, 64);
                a6 += __shfl_xor(a6, 16, 64); a6 += __shfl_xor(a6, 32, 64);
                a7 += __shfl_xor(a7, 16, 64); a7 += __shfl_xor(a7, 32, 64);

                if (grp == 0) {
                    float inv = invd[node];
                    uint4 self = hb4[(size_t)node * 16 + cidx];
                    unsigned o0 = f2bf(bflo(self.x) + a0 * inv) | (f2bf(bfhi(self.x) + a1 * inv) << 16);
                    unsigned o1 = f2bf(bflo(self.y) + a2 * inv) | (f2bf(bfhi(self.y) + a3 * inv) << 16);
                    unsigned o2 = f2bf(bflo(self.z) + a4 * inv) | (f2bf(bfhi(self.z) + a5 * inv) << 16);
                    unsigned o3 = f2bf(bflo(self.w) + a6 * inv) | (f2bf(bfhi(self.w) + a7 * inv) << 16);
                    int sw = cidx ^ (node & 7);
                    *reinterpret_cast<uint4*>(aggx + (size_t)node * 64 + sw * 4) = make_uint4(o0, o1, o2, o3);
                }
            }
        }
        gbar();

        // ======== layer phase ========
        const unsigned short* Wt = Wt_all + (size_t)l * 128 * 128;
        const float* bias = b_all + l * HID;
        const float* g = g_all + l * HID;
        const float* lb2 = lnb_all + l * HID;
        const int na = *n_act_p;
        for (int tile = blockIdx.x; tile < tgrid; tile += gridDim.x) {
            const int row0 = tile * RT;
            const int xrow = w * 16 + l15;
            const int grow = row0 + xrow;
            const unsigned short* xg = reinterpret_cast<const unsigned short*>(aggx) + (size_t)grow * HID;

            f32x4 acc[8];
#pragma unroll
            for (int t = 0; t < 8; ++t) acc[t] = (f32x4){0.f, 0.f, 0.f, 0.f};
#pragma unroll
            for (int kc = 0; kc < 4; ++kc) {
                int bc = (kc * 4 + lg) ^ (xrow & 7);
                bf16x8 bfrag = *reinterpret_cast<const bf16x8*>(xg + bc * 8);
                const unsigned short* wp = Wt + (size_t)l15 * HID + kc * 32 + lg * 8;
                bf16x8 af[8];
#pragma unroll
                for (int t = 0; t < 8; ++t) af[t] = *reinterpret_cast<const bf16x8*>(wp + (size_t)t * 16 * HID);
#pragma unroll
                for (int t = 0; t < 8; ++t)
                    acc[t] = __builtin_amdgcn_mfma_f32_16x16x32_bf16(af[t], bfrag, acc[t], 0, 0, 0);
            }

            float s = 0.f, q = 0.f;
#pragma unroll
            for (int t = 0; t < 8; ++t) {
                int c0 = t * 16 + lg * 4;
                f32x4 bb = *reinterpret_cast<const f32x4*>(bias + c0);
                acc[t] = acc[t] + bb;
                s += acc[t].x + acc[t].y + acc[t].z + acc[t].w;
                q += acc[t].x * acc[t].x + acc[t].y * acc[t].y + acc[t].z * acc[t].z + acc[t].w * acc[t].w;
            }
            s += __shfl_xor(s, 16, 64);
            s += __shfl_xor(s, 32, 64);
            q += __shfl_xor(q, 16, 64);
            q += __shfl_xor(q, 32, 64);
            float mu = s * (1.0f / HID);
            float var = q * (1.0f / HID) - mu * mu;
            float rs = rsqrtf(var + LN_EPS);

            if (l < 2) {
                if (grow < n) {
#pragma unroll
                    for (int t = 0; t < 8; ++t) {
                        int c0 = t * 16 + lg * 4;
                        uint2 rv = *reinterpret_cast<const uint2*>(hin + (size_t)grow * 64 + t * 8 + lg * 2);
                        f32x4 gv = *reinterpret_cast<const f32x4*>(g + c0);
                        f32x4 lb = *reinterpret_cast<const f32x4*>(lb2 + c0);
                        float o0 = fmaxf((acc[t].x - mu) * rs * gv.x + lb.x, 0.f) + bflo(rv.x);
                        float o1 = fmaxf((acc[t].y - mu) * rs * gv.y + lb.y, 0.f) + bfhi(rv.x);
                        float o2 = fmaxf((acc[t].z - mu) * rs * gv.z + lb.z, 0.f) + bflo(rv.y);
                        float o3 = fmaxf((acc[t].w - mu) * rs * gv.w + lb.w, 0.f) + bfhi(rv.y);
                        uint2 p;
                        p.x = f2bf(o0) | (f2bf(o1) << 16);
                        p.y = f2bf(o2) | (f2bf(o3) << 16);
                        *reinterpret_cast<uint2*>(hout + (size_t)grow * 64 + t * 8 + lg * 2) = p;
                    }
                }
            } else {
                __shared__ float red[4][4][8][4];
                const float msk = (grow < na) ? 1.f : 0.f;
#pragma unroll
                for (int t = 0; t < 8; ++t) {
                    int c0 = t * 16 + lg * 4;
                    uint2 rv = *reinterpret_cast<const uint2*>(hin + (size_t)grow * 64 + t * 8 + lg * 2);
                    f32x4 gv = *reinterpret_cast<const f32x4*>(g + c0);
                    f32x4 lb = *reinterpret_cast<const f32x4*>(lb2 + c0);
                    float o0 = (fmaxf((acc[t].x - mu) * rs * gv.x + lb.x, 0.f) + bflo(rv.x)) * msk;
                    float o1 = (fmaxf((acc[t].y - mu) * rs * gv.y + lb.y, 0.f) + bfhi(rv.x)) * msk;
                    float o2 = (fmaxf((acc[t].z - mu) * rs * gv.z + lb.z, 0.f) + bflo(rv.y)) * msk;
                    float o3 = (fmaxf((acc[t].w - mu) * rs * gv.w + lb.w, 0.f) + bfhi(rv.y)) * msk;
#pragma unroll
                    for (int m = 1; m < 16; m <<= 1) {
                        o0 += __shfl_xor(o0, m, 64);
                        o1 += __shfl_xor(o1, m, 64);
                        o2 += __shfl_xor(o2, m, 64);
                        o3 += __shfl_xor(o3, m, 64);
                    }
                    if (l15 == 0) {
                        red[w][lg][t][0] = o0;
                        red[w][lg][t][1] = o1;
                        red[w][lg][t][2] = o2;
                        red[w][lg][t][3] = o3;
                    }
                }
                __syncthreads();
                if (tid < HID) {
                    int t = tid >> 4, rem = tid & 15;
                    int lgq = rem >> 2, j = rem & 3;
                    float v = red[0][lgq][t][j] + red[1][lgq][t][j] + red[2][lgq][t][j] + red[3][lgq][t][j];
                    atomicAdd(&accum[tid], v);
                }
                __syncthreads();   // protect red for next tile iteration
            }
        }
        gbar();
        if (l < 2) {
            const unsigned* t = hout;
            hout = (unsigned*)hin;
            hin = t;
        }
    }

    // ======== out phase: block 0 ========
    if (blockIdx.x == 0) {
        __shared__ float m[HID];
        if (tid < HID) m[tid] = accum[tid] / (float)(*n_act_p);
        __syncthreads();
        if (tid < HID) {
            float s = b_o[tid];
            for (int k = 0; k < HID; ++k) s += m[k] * W_o[k * HID + tid];
            out[tid] = s;
        }
    }
}

extern "C" void kernel_launch(void* const* d_in, const int* in_sizes, int n_in,
                              void* d_out, int out_size, void* d_ws, size_t ws_size,
                              hipStream_t stream) {
    const int n  = in_sizes[0] / INP;   // 50000
    const int nE = in_sizes[1] / 2;     // 800000
    const float* x    = (const float*)d_in[0];
    const int*   ei   = (const int*)d_in[1];
    const int*   src  = ei;
    const int*   dst  = ei + nE;
    const int*   nact = (const int*)d_in[2];
    const float* W_in = (const float*)d_in[3];
    const float* b_in = (const float*)d_in[4];
    const float* W_l  = (const float*)d_in[5];
    const float* b_l  = (const float*)d_in[6];
    const float* lng  = (const float*)d_in[7];
    const float* lnb  = (const float*)d_in[8];
    const float* W_o  = (const float*)d_in[9];
    const float* b_o  = (const float*)d_in[10];

    char* ws = (char*)d_ws;
    size_t off = 0;
    auto alloc = [&](size_t bytes) {
        void* p = ws + off;
        off = (off + bytes + 255) & ~((size_t)255);
        return p;
    };
    unsigned* hbA  = (unsigned*)alloc((size_t)n * 64 * 4);
    unsigned* hbB  = (unsigned*)alloc((size_t)n * 64 * 4);
    unsigned* aggx = (unsigned*)alloc((size_t)(n + RT) * 64 * 4);  // +RT rows pad for tail-block frag reads
    size_t cntBytes = (((size_t)n * 4) + 255) & ~((size_t)255);
    int*   cnt   = (int*)alloc(cntBytes);
    float* accum = (float*)alloc(HID * 4);   // contiguous with cnt
    int*   bar   = (int*)alloc(4096);        // barrier state, contiguous with accum
    int*   rowp = (int*)alloc((size_t)(n + 1) * 4);
    float* invd = (float*)alloc((size_t)n * 4);
    int*   csrc = (int*)alloc((size_t)nE * 4);
    int*   rank = (int*)alloc((size_t)nE * 4);
    int*   bsum = (int*)alloc(1024);
    unsigned short* Wt_in = (unsigned short*)alloc(128 * 64 * 2);
    unsigned short* Wt_l  = (unsigned short*)alloc(3 * 128 * 128 * 2);

    // one memset covers cnt + accum + bar (contiguous allocs); re-zeroed every launch/replay
    hipMemsetAsync(cnt, 0, cntBytes + 512 + 4096, stream);

    int nb = (n + 255) / 256;
    int nEdgeThreads = (nE + 15) / 16;                       // 16 edges/thread
    int nPrep = 128 * 64 + 3 * 128 * 128;
    int cpgrid = (nEdgeThreads + nPrep + 255) / 256;
    k_count<<<cpgrid, 256, 0, stream>>>(dst, nE, cnt, rank, nEdgeThreads, W_in, W_l, Wt_in, Wt_l);
    k_scan1<<<nb, 256, 0, stream>>>(cnt, n, rowp, bsum);
    k_scan3<<<nb, 256, 0, stream>>>(rowp, bsum, cnt, n, nE, invd, nb);

    int tgrid = (n + RT - 1) / RT;
    int fgrid = (nEdgeThreads + 255) / 256;
    k_fillproj<<<tgrid + fgrid, 256, 0, stream>>>(x, Wt_in, b_in, hbA, n, tgrid,
                                                  src, dst, rank, rowp, nE, csrc);

    const int G = 768;   // 3 blocks/CU x 256 CUs, guaranteed by __launch_bounds__(256,3); G % 8 == 0
    k_net<<<G, 256, 0, stream>>>(hbA, hbB, aggx, rowp, csrc, invd,
                                 Wt_l, b_l, lng, lnb, nact, accum,
                                 W_o, b_o, (float*)d_out, n, tgrid, bar);
}

// Round 14
// 324.769 us; speedup vs baseline: 1.6852x; 1.6852x over previous
//
#include <hip/hip_runtime.h>

#define HID 128
#define INP 64
#define LN_EPS 1e-5f
#define RT 64   // rows per block in GEMM kernels

typedef __attribute__((ext_vector_type(8))) short bf16x8;
typedef __attribute__((ext_vector_type(4))) float f32x4;

__device__ __forceinline__ unsigned f2bf(float f) {
    unsigned u = __float_as_uint(f);
    return (u + 0x7FFFu + ((u >> 16) & 1u)) >> 16;   // RNE
}
__device__ __forceinline__ float bflo(unsigned v) { return __uint_as_float(v << 16); }
__device__ __forceinline__ float bfhi(unsigned v) { return __uint_as_float(v & 0xFFFF0000u); }

// ---------------- CSR count (16 edges/thread, records per-edge rank) + fused weight prep ----------------
__global__ __launch_bounds__(256) void k_count(const int* __restrict__ dst, int nE, int* __restrict__ cnt,
                                               int* __restrict__ rank, int nEdgeThreads,
                                               const float* __restrict__ W_in, const float* __restrict__ W_l,
                                               unsigned short* __restrict__ Wt_in, unsigned short* __restrict__ Wt_l) {
    int t = blockIdx.x * 256 + threadIdx.x;
    if (t < nEdgeThreads) {
        int base = t * 16;
        if (base + 16 <= nE) {
            int4 d[4];
#pragma unroll
            for (int j = 0; j < 4; ++j) d[j] = *reinterpret_cast<const int4*>(dst + base + j * 4);
            int p[16];
#pragma unroll
            for (int j = 0; j < 4; ++j) {
                p[j * 4 + 0] = atomicAdd(&cnt[d[j].x], 1);
                p[j * 4 + 1] = atomicAdd(&cnt[d[j].y], 1);
                p[j * 4 + 2] = atomicAdd(&cnt[d[j].z], 1);
                p[j * 4 + 3] = atomicAdd(&cnt[d[j].w], 1);
            }
#pragma unroll
            for (int j = 0; j < 4; ++j)
                *reinterpret_cast<int4*>(rank + base + j * 4) =
                    make_int4(p[j * 4 + 0], p[j * 4 + 1], p[j * 4 + 2], p[j * 4 + 3]);
        } else {
            for (int e = base; e < nE; ++e) rank[e] = atomicAdd(&cnt[dst[e]], 1);
        }
        return;
    }
    int i = t - nEdgeThreads;
    if (i < 128 * 64) {
        int col = i >> 6, k = i & 63;
        Wt_in[i] = (unsigned short)f2bf(W_in[(size_t)k * HID + col]);
    } else if (i < 128 * 64 + 3 * 128 * 128) {
        int j = i - 128 * 64;
        int l = j >> 14, r = j & 16383;
        int col = r >> 7, k = r & 127;
        Wt_l[j] = (unsigned short)f2bf(W_l[(size_t)l * 16384 + (size_t)k * HID + col]);
    }
}

// ---------------- single-pass scan: local scan -> device barrier (nb<=256 blocks, all resident) -> offset ----------------
__global__ void k_scan(const int* __restrict__ cnt, int n, int* __restrict__ rowp, int* __restrict__ bsum,
                       float* __restrict__ invd, int nE, int nb, int* __restrict__ sync) {
    __shared__ int s[256];
    __shared__ int boff;
    int i = blockIdx.x * 256 + threadIdx.x;
    int v = (i < n) ? cnt[i] : 0;
    s[threadIdx.x] = v;
    __syncthreads();
    for (int off = 1; off < 256; off <<= 1) {
        int t = (threadIdx.x >= off) ? s[threadIdx.x - off] : 0;
        __syncthreads();
        s[threadIdx.x] += t;
        __syncthreads();
    }
    int local_ex = s[threadIdx.x] - v;
    if (threadIdx.x == 255) bsum[blockIdx.x] = s[255];
    // device barrier across nb co-resident blocks
    __syncthreads();
    __threadfence();
    if (threadIdx.x == 0) {
        atomicAdd(&sync[0], 1);
        while (atomicAdd(&sync[0], 0) < nb) __builtin_amdgcn_s_sleep(2);
    }
    __syncthreads();
    __threadfence();
    // scan block sums (nb <= 256)
    int bv = (threadIdx.x < nb) ? bsum[threadIdx.x] : 0;
    s[threadIdx.x] = bv;
    __syncthreads();
    for (int off = 1; off < 256; off <<= 1) {
        int t = (threadIdx.x >= off) ? s[threadIdx.x - off] : 0;
        __syncthreads();
        s[threadIdx.x] += t;
        __syncthreads();
    }
    if (threadIdx.x == blockIdx.x) boff = s[threadIdx.x] - bv;
    __syncthreads();
    if (i < n) {
        rowp[i] = local_ex + boff;
        int c = cnt[i];
        invd[i] = 1.0f / (float)(c > 1 ? c : 1);
    } else if (i == n) {
        rowp[n] = nE;
    }
}

// ---------------- fused: [0,tgrid) in-projection MFMA; [tgrid,..) atomic-free CSR fill ----------------
__global__ __launch_bounds__(256) void k_fillproj(const float* __restrict__ x,
                                                  const unsigned short* __restrict__ Wt,  // [128][64] bf16
                                                  const float* __restrict__ b,
                                                  unsigned* __restrict__ hout, int n, int tgrid,
                                                  const int* __restrict__ src, const int* __restrict__ dst,
                                                  const int* __restrict__ rank, const int* __restrict__ rowp,
                                                  int nE, int* __restrict__ csrc) {
    const int tid = threadIdx.x;
    if (blockIdx.x >= tgrid) {
        int t = (blockIdx.x - tgrid) * 256 + tid;
        int base = t * 16;
        if (base + 16 <= nE) {
            int4 d[4], s[4], r[4];
#pragma unroll
            for (int j = 0; j < 4; ++j) {
                d[j] = *reinterpret_cast<const int4*>(dst + base + j * 4);
                s[j] = *reinterpret_cast<const int4*>(src + base + j * 4);
                r[j] = *reinterpret_cast<const int4*>(rank + base + j * 4);
            }
#pragma unroll
            for (int j = 0; j < 4; ++j) {
                __builtin_nontemporal_store(s[j].x, &csrc[rowp[d[j].x] + r[j].x]);
                __builtin_nontemporal_store(s[j].y, &csrc[rowp[d[j].y] + r[j].y]);
                __builtin_nontemporal_store(s[j].z, &csrc[rowp[d[j].z] + r[j].z]);
                __builtin_nontemporal_store(s[j].w, &csrc[rowp[d[j].w] + r[j].w]);
            }
        } else if (base < nE) {
            for (int e = base; e < nE; ++e)
                __builtin_nontemporal_store(src[e], &csrc[rowp[dst[e]] + rank[e]]);
        }
        return;
    }
    __shared__ unsigned short xs[RT * INP];  // 8 KB, swizzled
    const int row0 = blockIdx.x * RT;
#pragma unroll
    for (int j = 0; j < 2; ++j) {
        int fid = tid + j * 256;
        int r = fid >> 3, c = fid & 7;
        int grow = row0 + r;
        unsigned o[4] = {0, 0, 0, 0};
        if (grow < n) {
            float4 v0 = *reinterpret_cast<const float4*>(x + (size_t)grow * INP + c * 8);
            float4 v1 = *reinterpret_cast<const float4*>(x + (size_t)grow * INP + c * 8 + 4);
            o[0] = f2bf(v0.x) | (f2bf(v0.y) << 16);
            o[1] = f2bf(v0.z) | (f2bf(v0.w) << 16);
            o[2] = f2bf(v1.x) | (f2bf(v1.y) << 16);
            o[3] = f2bf(v1.z) | (f2bf(v1.w) << 16);
        }
        int sw = c ^ (r & 7);
        *reinterpret_cast<uint4*>(xs + r * INP + sw * 8) = make_uint4(o[0], o[1], o[2], o[3]);
    }
    __syncthreads();

    const int l = tid & 63;
    const int w = tid >> 6;
    const int l15 = l & 15, lg = l >> 4;
    const int xrow = w * 16 + l15;

    f32x4 acc[8];
#pragma unroll
    for (int t = 0; t < 8; ++t) acc[t] = (f32x4){0.f, 0.f, 0.f, 0.f};

#pragma unroll
    for (int kc = 0; kc < 2; ++kc) {
        int bc = (kc * 4 + lg) ^ (xrow & 7);
        bf16x8 bfrag = *reinterpret_cast<const bf16x8*>(xs + xrow * INP + bc * 8);
        const unsigned short* wp = Wt + (size_t)l15 * INP + kc * 32 + lg * 8;
        bf16x8 af[8];
#pragma unroll
        for (int t = 0; t < 8; ++t) af[t] = *reinterpret_cast<const bf16x8*>(wp + (size_t)t * 16 * INP);
#pragma unroll
        for (int t = 0; t < 8; ++t)
            acc[t] = __builtin_amdgcn_mfma_f32_16x16x32_bf16(af[t], bfrag, acc[t], 0, 0, 0);
    }

    int grow = row0 + xrow;
    if (grow < n) {
#pragma unroll
        for (int t = 0; t < 8; ++t) {
            int c0 = t * 16 + lg * 4;
            f32x4 bb = *reinterpret_cast<const f32x4*>(b + c0);
            f32x4 o = acc[t] + bb;
            uint2 p;
            p.x = f2bf(o.x) | (f2bf(o.y) << 16);
            p.y = f2bf(o.z) | (f2bf(o.w) << 16);
            *reinterpret_cast<uint2*>(hout + (size_t)grow * 64 + t * 8 + lg * 2) = p;
        }
    }
}

// ---------------- aggregation (uint4 gather: 4 edges/wave-instruction) ----------------
// aggx[v] = bf16( hb[v] + (sum_{u in N(v)} hb[u]) * invd[v] ), PRE-SWIZZLED
__global__ __launch_bounds__(256) void k_agg(const unsigned* __restrict__ hb, const int* __restrict__ rowp,
                                             const int* __restrict__ csrc, const float* __restrict__ invd,
                                             unsigned* __restrict__ aggx, int n) {
    int node = blockIdx.x * 4 + (threadIdx.x >> 6);
    if (node >= n) return;
    int lane = threadIdx.x & 63;
    int grp = lane >> 4, cidx = lane & 15;
    int e0 = rowp[node], e1 = rowp[node + 1];
    int deg = e1 - e0;
    const uint4* hb4 = reinterpret_cast<const uint4*>(hb);
    float a0 = 0, a1 = 0, a2 = 0, a3 = 0, a4 = 0, a5 = 0, a6 = 0, a7 = 0;

    for (int base = 0; base < deg; base += 64) {
        int m = deg - base;
        if (m > 64) m = 64;
        int myidx = (base + lane < deg) ? csrc[e0 + base + lane] : 0;
        int steps = (m + 3) >> 2;   // groups of 4 edges
        int jj = 0;
        for (; jj + 4 <= steps; jj += 4) {
            uint4 v[4];
#pragma unroll
            for (int k = 0; k < 4; ++k) {
                int ei = (jj + k) * 4 + grp;
                int s = __shfl(myidx, ei);
                v[k] = (ei < m) ? hb4[(size_t)s * 16 + cidx] : make_uint4(0, 0, 0, 0);
            }
#pragma unroll
            for (int k = 0; k < 4; ++k) {
                a0 += bflo(v[k].x); a1 += bfhi(v[k].x);
                a2 += bflo(v[k].y); a3 += bfhi(v[k].y);
                a4 += bflo(v[k].z); a5 += bfhi(v[k].z);
                a6 += bflo(v[k].w); a7 += bfhi(v[k].w);
            }
        }
        for (; jj < steps; ++jj) {
            int ei = jj * 4 + grp;
            int s = __shfl(myidx, ei);
            if (ei < m) {
                uint4 v = hb4[(size_t)s * 16 + cidx];
                a0 += bflo(v.x); a1 += bfhi(v.x);
                a2 += bflo(v.y); a3 += bfhi(v.y);
                a4 += bflo(v.z); a5 += bfhi(v.z);
                a6 += bflo(v.w); a7 += bfhi(v.w);
            }
        }
    }
    // reduce across the 4 edge-groups (lanes xor 16, 32 hold same column chunk)
    a0 += __shfl_xor(a0, 16, 64); a0 += __shfl_xor(a0, 32, 64);
    a1 += __shfl_xor(a1, 16, 64); a1 += __shfl_xor(a1, 32, 64);
    a2 += __shfl_xor(a2, 16, 64); a2 += __shfl_xor(a2, 32, 64);
    a3 += __shfl_xor(a3, 16, 64); a3 += __shfl_xor(a3, 32, 64);
    a4 += __shfl_xor(a4, 16, 64); a4 += __shfl_xor(a4, 32, 64);
    a5 += __shfl_xor(a5, 16, 64); a5 += __shfl_xor(a5, 32, 64);
    a6 += __shfl_xor(a6, 16, 64); a6 += __shfl_xor(a6, 32, 64);
    a7 += __shfl_xor(a7, 16, 64); a7 += __shfl_xor(a7, 32, 64);

    if (grp == 0) {  // lanes 0..15 write the full row
        float inv = invd[node];
        uint4 self = hb4[(size_t)node * 16 + cidx];
        unsigned o0 = f2bf(bflo(self.x) + a0 * inv) | (f2bf(bfhi(self.x) + a1 * inv) << 16);
        unsigned o1 = f2bf(bflo(self.y) + a2 * inv) | (f2bf(bfhi(self.y) + a3 * inv) << 16);
        unsigned o2 = f2bf(bflo(self.z) + a4 * inv) | (f2bf(bfhi(self.z) + a5 * inv) << 16);
        unsigned o3 = f2bf(bflo(self.w) + a6 * inv) | (f2bf(bfhi(self.w) + a7 * inv) << 16);
        int sw = cidx ^ (node & 7);  // 16B chunk swizzle within the 256B row
        *reinterpret_cast<uint4*>(aggx + (size_t)node * 64 + sw * 4) = make_uint4(o0, o1, o2, o3);
    }
}

// ---------------- layer MFMA (no LDS): hout = relu(LN(X@W + b)*g + lnb) + hin ----------------
__global__ __launch_bounds__(256) void k_layer(const unsigned* __restrict__ hin,
                                               unsigned* __restrict__ hout,
                                               const unsigned* __restrict__ aggx,
                                               const unsigned short* __restrict__ Wt,
                                               const float* __restrict__ bias, const float* __restrict__ g,
                                               const float* __restrict__ lnb, int n) {
    const int tid = threadIdx.x;
    const int row0 = blockIdx.x * RT;
    const int lane = tid & 63;
    const int w = tid >> 6;
    const int l15 = lane & 15, lg = lane >> 4;
    const int xrow = w * 16 + l15;
    const int grow = row0 + xrow;

    const unsigned short* xg = reinterpret_cast<const unsigned short*>(aggx) + (size_t)grow * HID;

    f32x4 acc[8];
#pragma unroll
    for (int t = 0; t < 8; ++t) acc[t] = (f32x4){0.f, 0.f, 0.f, 0.f};

#pragma unroll
    for (int kc = 0; kc < 4; ++kc) {
        int bc = (kc * 4 + lg) ^ (xrow & 7);
        bf16x8 bfrag = *reinterpret_cast<const bf16x8*>(xg + bc * 8);
        const unsigned short* wp = Wt + (size_t)l15 * HID + kc * 32 + lg * 8;
        bf16x8 af[8];
#pragma unroll
        for (int t = 0; t < 8; ++t) af[t] = *reinterpret_cast<const bf16x8*>(wp + (size_t)t * 16 * HID);
#pragma unroll
        for (int t = 0; t < 8; ++t)
            acc[t] = __builtin_amdgcn_mfma_f32_16x16x32_bf16(af[t], bfrag, acc[t], 0, 0, 0);
    }

    float s = 0.f, q = 0.f;
#pragma unroll
    for (int t = 0; t < 8; ++t) {
        int c0 = t * 16 + lg * 4;
        f32x4 bb = *reinterpret_cast<const f32x4*>(bias + c0);
        acc[t] = acc[t] + bb;
        s += acc[t].x + acc[t].y + acc[t].z + acc[t].w;
        q += acc[t].x * acc[t].x + acc[t].y * acc[t].y + acc[t].z * acc[t].z + acc[t].w * acc[t].w;
    }
    s += __shfl_xor(s, 16, 64);
    s += __shfl_xor(s, 32, 64);
    q += __shfl_xor(q, 16, 64);
    q += __shfl_xor(q, 32, 64);
    float mu = s * (1.0f / HID);
    float var = q * (1.0f / HID) - mu * mu;
    float rs = rsqrtf(var + LN_EPS);

    if (grow < n) {
#pragma unroll
        for (int t = 0; t < 8; ++t) {
            int c0 = t * 16 + lg * 4;
            uint2 rv = *reinterpret_cast<const uint2*>(hin + (size_t)grow * 64 + t * 8 + lg * 2);
            f32x4 gv = *reinterpret_cast<const f32x4*>(g + c0);
            f32x4 lb = *reinterpret_cast<const f32x4*>(lnb + c0);
            float o0 = fmaxf((acc[t].x - mu) * rs * gv.x + lb.x, 0.f) + bflo(rv.x);
            float o1 = fmaxf((acc[t].y - mu) * rs * gv.y + lb.y, 0.f) + bfhi(rv.x);
            float o2 = fmaxf((acc[t].z - mu) * rs * gv.z + lb.z, 0.f) + bflo(rv.y);
            float o3 = fmaxf((acc[t].w - mu) * rs * gv.w + lb.w, 0.f) + bfhi(rv.y);
            uint2 p;
            p.x = f2bf(o0) | (f2bf(o1) << 16);
            p.y = f2bf(o2) | (f2bf(o3) << 16);
            *reinterpret_cast<uint2*>(hout + (size_t)grow * 64 + t * 8 + lg * 2) = p;
        }
    }
}

// ---------------- FINAL layer: fused masked column-sum + last-block output matvec ----------------
__global__ __launch_bounds__(256) void k_layerF(const unsigned* __restrict__ hin,
                                                const unsigned* __restrict__ aggx,
                                                const unsigned short* __restrict__ Wt,
                                                const float* __restrict__ bias, const float* __restrict__ g,
                                                const float* __restrict__ lnb,
                                                const int* __restrict__ n_act_p,
                                                float* __restrict__ accum,
                                                const float* __restrict__ W_o, const float* __restrict__ b_o,
                                                float* __restrict__ out, int tgrid, int* __restrict__ done) {
    __shared__ float red[4][4][8][4];   // [wave][lg][t][j] = 2 KB
    __shared__ int lastFlag;
    const int tid = threadIdx.x;
    const int row0 = blockIdx.x * RT;
    const int lane = tid & 63;
    const int w = tid >> 6;
    const int l15 = lane & 15, lg = lane >> 4;
    const int xrow = w * 16 + l15;
    const int grow = row0 + xrow;
    const int na = *n_act_p;

    const unsigned short* xg = reinterpret_cast<const unsigned short*>(aggx) + (size_t)grow * HID;

    f32x4 acc[8];
#pragma unroll
    for (int t = 0; t < 8; ++t) acc[t] = (f32x4){0.f, 0.f, 0.f, 0.f};

#pragma unroll
    for (int kc = 0; kc < 4; ++kc) {
        int bc = (kc * 4 + lg) ^ (xrow & 7);
        bf16x8 bfrag = *reinterpret_cast<const bf16x8*>(xg + bc * 8);
        const unsigned short* wp = Wt + (size_t)l15 * HID + kc * 32 + lg * 8;
        bf16x8 af[8];
#pragma unroll
        for (int t = 0; t < 8; ++t) af[t] = *reinterpret_cast<const bf16x8*>(wp + (size_t)t * 16 * HID);
#pragma unroll
        for (int t = 0; t < 8; ++t)
            acc[t] = __builtin_amdgcn_mfma_f32_16x16x32_bf16(af[t], bfrag, acc[t], 0, 0, 0);
    }

    float s = 0.f, q = 0.f;
#pragma unroll
    for (int t = 0; t < 8; ++t) {
        int c0 = t * 16 + lg * 4;
        f32x4 bb = *reinterpret_cast<const f32x4*>(bias + c0);
        acc[t] = acc[t] + bb;
        s += acc[t].x + acc[t].y + acc[t].z + acc[t].w;
        q += acc[t].x * acc[t].x + acc[t].y * acc[t].y + acc[t].z * acc[t].z + acc[t].w * acc[t].w;
    }
    s += __shfl_xor(s, 16, 64);
    s += __shfl_xor(s, 32, 64);
    q += __shfl_xor(q, 16, 64);
    q += __shfl_xor(q, 32, 64);
    float mu = s * (1.0f / HID);
    float var = q * (1.0f / HID) - mu * mu;
    float rs = rsqrtf(var + LN_EPS);

    const float msk = (grow < na) ? 1.f : 0.f;   // rows >= na (incl. tail garbage) contribute 0
#pragma unroll
    for (int t = 0; t < 8; ++t) {
        int c0 = t * 16 + lg * 4;
        uint2 rv = *reinterpret_cast<const uint2*>(hin + (size_t)grow * 64 + t * 8 + lg * 2);
        f32x4 gv = *reinterpret_cast<const f32x4*>(g + c0);
        f32x4 lb = *reinterpret_cast<const f32x4*>(lnb + c0);
        float o0 = (fmaxf((acc[t].x - mu) * rs * gv.x + lb.x, 0.f) + bflo(rv.x)) * msk;
        float o1 = (fmaxf((acc[t].y - mu) * rs * gv.y + lb.y, 0.f) + bfhi(rv.x)) * msk;
        float o2 = (fmaxf((acc[t].z - mu) * rs * gv.z + lb.z, 0.f) + bflo(rv.y)) * msk;
        float o3 = (fmaxf((acc[t].w - mu) * rs * gv.w + lb.w, 0.f) + bfhi(rv.y)) * msk;
#pragma unroll
        for (int m = 1; m < 16; m <<= 1) {
            o0 += __shfl_xor(o0, m, 64);
            o1 += __shfl_xor(o1, m, 64);
            o2 += __shfl_xor(o2, m, 64);
            o3 += __shfl_xor(o3, m, 64);
        }
        if (l15 == 0) {
            red[w][lg][t][0] = o0;
            red[w][lg][t][1] = o1;
            red[w][lg][t][2] = o2;
            red[w][lg][t][3] = o3;
        }
    }
    __syncthreads();
    if (tid < HID) {
        int t = tid >> 4, rem = tid & 15;
        int lgq = rem >> 2, j = rem & 3;
        float v = red[0][lgq][t][j] + red[1][lgq][t][j] + red[2][lgq][t][j] + red[3][lgq][t][j];
        atomicAdd(&accum[tid], v);
    }
    // last finished block computes the output matvec
    __syncthreads();
    __threadfence();
    if (tid == 0) lastFlag = (atomicAdd(done, 1) == tgrid - 1) ? 1 : 0;
    __syncthreads();
    if (lastFlag) {
        __shared__ float m[HID];
        __threadfence();
        if (tid < HID) m[tid] = atomicAdd(&accum[tid], 0.f) / (float)na;
        __syncthreads();
        if (tid < HID) {
            float o = b_o[tid];
            for (int k = 0; k < HID; ++k) o += m[k] * W_o[k * HID + tid];
            out[tid] = o;
        }
    }
}

extern "C" void kernel_launch(void* const* d_in, const int* in_sizes, int n_in,
                              void* d_out, int out_size, void* d_ws, size_t ws_size,
                              hipStream_t stream) {
    const int n  = in_sizes[0] / INP;   // 50000
    const int nE = in_sizes[1] / 2;     // 800000
    const float* x    = (const float*)d_in[0];
    const int*   ei   = (const int*)d_in[1];
    const int*   src  = ei;
    const int*   dst  = ei + nE;
    const int*   nact = (const int*)d_in[2];
    const float* W_in = (const float*)d_in[3];
    const float* b_in = (const float*)d_in[4];
    const float* W_l  = (const float*)d_in[5];
    const float* b_l  = (const float*)d_in[6];
    const float* lng  = (const float*)d_in[7];
    const float* lnb  = (const float*)d_in[8];
    const float* W_o  = (const float*)d_in[9];
    const float* b_o  = (const float*)d_in[10];

    char* ws = (char*)d_ws;
    size_t off = 0;
    auto alloc = [&](size_t bytes) {
        void* p = ws + off;
        off = (off + bytes + 255) & ~((size_t)255);
        return p;
    };
    unsigned* hbA  = (unsigned*)alloc((size_t)n * 64 * 4);
    unsigned* hbB  = (unsigned*)alloc((size_t)n * 64 * 4);
    unsigned* aggx = (unsigned*)alloc((size_t)(n + RT) * 64 * 4);  // +RT rows pad for tail-block frag reads
    size_t cntBytes = (((size_t)n * 4) + 255) & ~((size_t)255);
    int*   cnt   = (int*)alloc(cntBytes);
    float* accum = (float*)alloc(HID * 4);   // contiguous with cnt (512 B)
    int*   sync  = (int*)alloc(256);         // [0]=scan arrivals, [16]=layerF done; contiguous
    int*   rowp = (int*)alloc((size_t)(n + 1) * 4);
    float* invd = (float*)alloc((size_t)n * 4);
    int*   csrc = (int*)alloc((size_t)nE * 4);
    int*   rank = (int*)alloc((size_t)nE * 4);
    int*   bsum = (int*)alloc(1024);
    unsigned short* Wt_in = (unsigned short*)alloc(128 * 64 * 2);
    unsigned short* Wt_l  = (unsigned short*)alloc(3 * 128 * 128 * 2);

    // one memset covers cnt + accum + sync (contiguous); re-zeroed every launch/replay
    hipMemsetAsync(cnt, 0, cntBytes + 512 + 256, stream);

    int nb = (n + 255) / 256;   // 196 <= 256: k_scan's internal barrier is safe (all blocks resident)
    int nEdgeThreads = (nE + 15) / 16;                       // 16 edges/thread
    int nPrep = 128 * 64 + 3 * 128 * 128;
    int cpgrid = (nEdgeThreads + nPrep + 255) / 256;
    k_count<<<cpgrid, 256, 0, stream>>>(dst, nE, cnt, rank, nEdgeThreads, W_in, W_l, Wt_in, Wt_l);
    k_scan<<<nb, 256, 0, stream>>>(cnt, n, rowp, bsum, invd, nE, nb, sync);

    int tgrid = (n + RT - 1) / RT;
    int fgrid = (nEdgeThreads + 255) / 256;
    k_fillproj<<<tgrid + fgrid, 256, 0, stream>>>(x, Wt_in, b_in, hbA, n, tgrid,
                                                  src, dst, rank, rowp, nE, csrc);

    const unsigned* hin = hbA;
    unsigned* hout = hbB;
    for (int l = 0; l < 3; ++l) {
        k_agg<<<(n + 3) / 4, 256, 0, stream>>>(hin, rowp, csrc, invd, aggx, n);
        if (l < 2) {
            k_layer<<<tgrid, 256, 0, stream>>>(hin, hout, aggx,
                                               Wt_l + (size_t)l * 128 * 128,
                                               b_l + l * HID, lng + l * HID, lnb + l * HID, n);
            const unsigned* t = hout;
            hout = (unsigned*)hin;
            hin = t;
        } else {
            k_layerF<<<tgrid, 256, 0, stream>>>(hin, aggx,
                                                Wt_l + (size_t)l * 128 * 128,
                                                b_l + l * HID, lng + l * HID, lnb + l * HID,
                                                nact, accum, W_o, b_o, (float*)d_out,
                                                tgrid, sync + 16);
        }
    }
}

// Round 15
// 266.643 us; speedup vs baseline: 2.0525x; 1.2180x over previous
//
#include <hip/hip_runtime.h>

#define HID 128
#define INP 64
#define LN_EPS 1e-5f
#define RT 64   // rows per block in GEMM kernels

typedef __attribute__((ext_vector_type(8))) short bf16x8;
typedef __attribute__((ext_vector_type(4))) float f32x4;

__device__ __forceinline__ unsigned f2bf(float f) {
    unsigned u = __float_as_uint(f);
    return (u + 0x7FFFu + ((u >> 16) & 1u)) >> 16;   // RNE
}
__device__ __forceinline__ float bflo(unsigned v) { return __uint_as_float(v << 16); }
__device__ __forceinline__ float bfhi(unsigned v) { return __uint_as_float(v & 0xFFFF0000u); }

// ---------------- CSR count (16 edges/thread, records per-edge rank) + fused weight prep ----------------
__global__ __launch_bounds__(256) void k_count(const int* __restrict__ dst, int nE, int* __restrict__ cnt,
                                               int* __restrict__ rank, int nEdgeThreads,
                                               const float* __restrict__ W_in, const float* __restrict__ W_l,
                                               unsigned short* __restrict__ Wt_in, unsigned short* __restrict__ Wt_l) {
    int t = blockIdx.x * 256 + threadIdx.x;
    if (t < nEdgeThreads) {
        int base = t * 16;
        if (base + 16 <= nE) {
            int4 d[4];
#pragma unroll
            for (int j = 0; j < 4; ++j) d[j] = *reinterpret_cast<const int4*>(dst + base + j * 4);
            int p[16];
#pragma unroll
            for (int j = 0; j < 4; ++j) {
                p[j * 4 + 0] = atomicAdd(&cnt[d[j].x], 1);
                p[j * 4 + 1] = atomicAdd(&cnt[d[j].y], 1);
                p[j * 4 + 2] = atomicAdd(&cnt[d[j].z], 1);
                p[j * 4 + 3] = atomicAdd(&cnt[d[j].w], 1);
            }
#pragma unroll
            for (int j = 0; j < 4; ++j)
                *reinterpret_cast<int4*>(rank + base + j * 4) =
                    make_int4(p[j * 4 + 0], p[j * 4 + 1], p[j * 4 + 2], p[j * 4 + 3]);
        } else {
            for (int e = base; e < nE; ++e) rank[e] = atomicAdd(&cnt[dst[e]], 1);
        }
        return;
    }
    int i = t - nEdgeThreads;
    if (i < 128 * 64) {
        int col = i >> 6, k = i & 63;
        Wt_in[i] = (unsigned short)f2bf(W_in[(size_t)k * HID + col]);
    } else if (i < 128 * 64 + 3 * 128 * 128) {
        int j = i - 128 * 64;
        int l = j >> 14, r = j & 16383;
        int col = r >> 7, k = r & 127;
        Wt_l[j] = (unsigned short)f2bf(W_l[(size_t)l * 16384 + (size_t)k * HID + col]);
    }
}

__global__ void k_scan1(const int* __restrict__ cnt, int n, int* __restrict__ rowp, int* __restrict__ bsum) {
    __shared__ int s[256];
    int i = blockIdx.x * 256 + threadIdx.x;
    int v = (i < n) ? cnt[i] : 0;
    s[threadIdx.x] = v;
    __syncthreads();
    for (int off = 1; off < 256; off <<= 1) {
        int t = (threadIdx.x >= off) ? s[threadIdx.x - off] : 0;
        __syncthreads();
        s[threadIdx.x] += t;
        __syncthreads();
    }
    if (i < n) rowp[i] = s[threadIdx.x] - v;  // exclusive (within block)
    if (threadIdx.x == 255) bsum[blockIdx.x] = s[255];
}

// scan3 with inline redundant scan of bsum (replaces scan2)
__global__ void k_scan3(int* __restrict__ rowp, const int* __restrict__ bsum, const int* __restrict__ cnt,
                        int n, int nE, float* __restrict__ invd, int nb) {
    __shared__ int s[256];
    __shared__ int boff;
    int v = (threadIdx.x < nb) ? bsum[threadIdx.x] : 0;
    s[threadIdx.x] = v;
    __syncthreads();
    for (int off = 1; off < 256; off <<= 1) {
        int t = (threadIdx.x >= off) ? s[threadIdx.x - off] : 0;
        __syncthreads();
        s[threadIdx.x] += t;
        __syncthreads();
    }
    if (threadIdx.x == blockIdx.x) boff = s[threadIdx.x] - v;  // exclusive prefix for this block
    __syncthreads();
    int i = blockIdx.x * 256 + threadIdx.x;
    if (i < n) {
        rowp[i] += boff;
        int c = cnt[i];
        invd[i] = 1.0f / (float)(c > 1 ? c : 1);
    } else if (i == n) {
        rowp[n] = nE;
    }
}

// ---------------- fused: [0,tgrid) in-projection MFMA; [tgrid,..) atomic-free CSR fill ----------------
__global__ __launch_bounds__(256) void k_fillproj(const float* __restrict__ x,
                                                  const unsigned short* __restrict__ Wt,  // [128][64] bf16
                                                  const float* __restrict__ b,
                                                  unsigned* __restrict__ hout, int n, int tgrid,
                                                  const int* __restrict__ src, const int* __restrict__ dst,
                                                  const int* __restrict__ rank, const int* __restrict__ rowp,
                                                  int nE, int* __restrict__ csrc) {
    const int tid = threadIdx.x;
    if (blockIdx.x >= tgrid) {
        int t = (blockIdx.x - tgrid) * 256 + tid;
        int base = t * 16;
        if (base + 16 <= nE) {
            int4 d[4], s[4], r[4];
#pragma unroll
            for (int j = 0; j < 4; ++j) {
                d[j] = *reinterpret_cast<const int4*>(dst + base + j * 4);
                s[j] = *reinterpret_cast<const int4*>(src + base + j * 4);
                r[j] = *reinterpret_cast<const int4*>(rank + base + j * 4);
            }
#pragma unroll
            for (int j = 0; j < 4; ++j) {
                __builtin_nontemporal_store(s[j].x, &csrc[rowp[d[j].x] + r[j].x]);
                __builtin_nontemporal_store(s[j].y, &csrc[rowp[d[j].y] + r[j].y]);
                __builtin_nontemporal_store(s[j].z, &csrc[rowp[d[j].z] + r[j].z]);
                __builtin_nontemporal_store(s[j].w, &csrc[rowp[d[j].w] + r[j].w]);
            }
        } else if (base < nE) {
            for (int e = base; e < nE; ++e)
                __builtin_nontemporal_store(src[e], &csrc[rowp[dst[e]] + rank[e]]);
        }
        return;
    }
    __shared__ unsigned short xs[RT * INP];  // 8 KB, swizzled
    const int row0 = blockIdx.x * RT;
#pragma unroll
    for (int j = 0; j < 2; ++j) {
        int fid = tid + j * 256;
        int r = fid >> 3, c = fid & 7;
        int grow = row0 + r;
        unsigned o[4] = {0, 0, 0, 0};
        if (grow < n) {
            float4 v0 = *reinterpret_cast<const float4*>(x + (size_t)grow * INP + c * 8);
            float4 v1 = *reinterpret_cast<const float4*>(x + (size_t)grow * INP + c * 8 + 4);
            o[0] = f2bf(v0.x) | (f2bf(v0.y) << 16);
            o[1] = f2bf(v0.z) | (f2bf(v0.w) << 16);
            o[2] = f2bf(v1.x) | (f2bf(v1.y) << 16);
            o[3] = f2bf(v1.z) | (f2bf(v1.w) << 16);
        }
        int sw = c ^ (r & 7);
        *reinterpret_cast<uint4*>(xs + r * INP + sw * 8) = make_uint4(o[0], o[1], o[2], o[3]);
    }
    __syncthreads();

    const int l = tid & 63;
    const int w = tid >> 6;
    const int l15 = l & 15, lg = l >> 4;
    const int xrow = w * 16 + l15;

    f32x4 acc[8];
#pragma unroll
    for (int t = 0; t < 8; ++t) acc[t] = (f32x4){0.f, 0.f, 0.f, 0.f};

#pragma unroll
    for (int kc = 0; kc < 2; ++kc) {
        int bc = (kc * 4 + lg) ^ (xrow & 7);
        bf16x8 bfrag = *reinterpret_cast<const bf16x8*>(xs + xrow * INP + bc * 8);
        const unsigned short* wp = Wt + (size_t)l15 * INP + kc * 32 + lg * 8;
        bf16x8 af[8];
#pragma unroll
        for (int t = 0; t < 8; ++t) af[t] = *reinterpret_cast<const bf16x8*>(wp + (size_t)t * 16 * INP);
#pragma unroll
        for (int t = 0; t < 8; ++t)
            acc[t] = __builtin_amdgcn_mfma_f32_16x16x32_bf16(af[t], bfrag, acc[t], 0, 0, 0);
    }

    int grow = row0 + xrow;
    if (grow < n) {
#pragma unroll
        for (int t = 0; t < 8; ++t) {
            int c0 = t * 16 + lg * 4;
            f32x4 bb = *reinterpret_cast<const f32x4*>(b + c0);
            f32x4 o = acc[t] + bb;
            uint2 p;
            p.x = f2bf(o.x) | (f2bf(o.y) << 16);
            p.y = f2bf(o.z) | (f2bf(o.w) << 16);
            *reinterpret_cast<uint2*>(hout + (size_t)grow * 64 + t * 8 + lg * 2) = p;
        }
    }
}

// ---------------- aggregation (uint4 gather: 4 edges/wave-instruction) ----------------
// aggx[v] = bf16( hb[v] + (sum_{u in N(v)} hb[u]) * invd[v] ), PRE-SWIZZLED
__global__ __launch_bounds__(256) void k_agg(const unsigned* __restrict__ hb, const int* __restrict__ rowp,
                                             const int* __restrict__ csrc, const float* __restrict__ invd,
                                             unsigned* __restrict__ aggx, int n) {
    int node = blockIdx.x * 4 + (threadIdx.x >> 6);
    if (node >= n) return;
    int lane = threadIdx.x & 63;
    int grp = lane >> 4, cidx = lane & 15;
    int e0 = rowp[node], e1 = rowp[node + 1];
    int deg = e1 - e0;
    const uint4* hb4 = reinterpret_cast<const uint4*>(hb);
    float a0 = 0, a1 = 0, a2 = 0, a3 = 0, a4 = 0, a5 = 0, a6 = 0, a7 = 0;

    for (int base = 0; base < deg; base += 64) {
        int m = deg - base;
        if (m > 64) m = 64;
        int myidx = (base + lane < deg) ? csrc[e0 + base + lane] : 0;
        int steps = (m + 3) >> 2;   // groups of 4 edges
        int jj = 0;
        for (; jj + 4 <= steps; jj += 4) {
            uint4 v[4];
#pragma unroll
            for (int k = 0; k < 4; ++k) {
                int ei = (jj + k) * 4 + grp;
                int s = __shfl(myidx, ei);
                v[k] = (ei < m) ? hb4[(size_t)s * 16 + cidx] : make_uint4(0, 0, 0, 0);
            }
#pragma unroll
            for (int k = 0; k < 4; ++k) {
                a0 += bflo(v[k].x); a1 += bfhi(v[k].x);
                a2 += bflo(v[k].y); a3 += bfhi(v[k].y);
                a4 += bflo(v[k].z); a5 += bfhi(v[k].z);
                a6 += bflo(v[k].w); a7 += bfhi(v[k].w);
            }
        }
        for (; jj < steps; ++jj) {
            int ei = jj * 4 + grp;
            int s = __shfl(myidx, ei);
            if (ei < m) {
                uint4 v = hb4[(size_t)s * 16 + cidx];
                a0 += bflo(v.x); a1 += bfhi(v.x);
                a2 += bflo(v.y); a3 += bfhi(v.y);
                a4 += bflo(v.z); a5 += bfhi(v.z);
                a6 += bflo(v.w); a7 += bfhi(v.w);
            }
        }
    }
    // reduce across the 4 edge-groups (lanes xor 16, 32 hold same column chunk)
    a0 += __shfl_xor(a0, 16, 64); a0 += __shfl_xor(a0, 32, 64);
    a1 += __shfl_xor(a1, 16, 64); a1 += __shfl_xor(a1, 32, 64);
    a2 += __shfl_xor(a2, 16, 64); a2 += __shfl_xor(a2, 32, 64);
    a3 += __shfl_xor(a3, 16, 64); a3 += __shfl_xor(a3, 32, 64);
    a4 += __shfl_xor(a4, 16, 64); a4 += __shfl_xor(a4, 32, 64);
    a5 += __shfl_xor(a5, 16, 64); a5 += __shfl_xor(a5, 32, 64);
    a6 += __shfl_xor(a6, 16, 64); a6 += __shfl_xor(a6, 32, 64);
    a7 += __shfl_xor(a7, 16, 64); a7 += __shfl_xor(a7, 32, 64);

    if (grp == 0) {  // lanes 0..15 write the full row
        float inv = invd[node];
        uint4 self = hb4[(size_t)node * 16 + cidx];
        unsigned o0 = f2bf(bflo(self.x) + a0 * inv) | (f2bf(bfhi(self.x) + a1 * inv) << 16);
        unsigned o1 = f2bf(bflo(self.y) + a2 * inv) | (f2bf(bfhi(self.y) + a3 * inv) << 16);
        unsigned o2 = f2bf(bflo(self.z) + a4 * inv) | (f2bf(bfhi(self.z) + a5 * inv) << 16);
        unsigned o3 = f2bf(bflo(self.w) + a6 * inv) | (f2bf(bfhi(self.w) + a7 * inv) << 16);
        int sw = cidx ^ (node & 7);  // 16B chunk swizzle within the 256B row
        *reinterpret_cast<uint4*>(aggx + (size_t)node * 64 + sw * 4) = make_uint4(o0, o1, o2, o3);
    }
}

// ---------------- layer MFMA (no LDS): hout = relu(LN(X@W + b)*g + lnb) + hin ----------------
__global__ __launch_bounds__(256) void k_layer(const unsigned* __restrict__ hin,
                                               unsigned* __restrict__ hout,
                                               const unsigned* __restrict__ aggx,
                                               const unsigned short* __restrict__ Wt,
                                               const float* __restrict__ bias, const float* __restrict__ g,
                                               const float* __restrict__ lnb, int n) {
    const int tid = threadIdx.x;
    const int row0 = blockIdx.x * RT;
    const int lane = tid & 63;
    const int w = tid >> 6;
    const int l15 = lane & 15, lg = lane >> 4;
    const int xrow = w * 16 + l15;
    const int grow = row0 + xrow;

    const unsigned short* xg = reinterpret_cast<const unsigned short*>(aggx) + (size_t)grow * HID;

    f32x4 acc[8];
#pragma unroll
    for (int t = 0; t < 8; ++t) acc[t] = (f32x4){0.f, 0.f, 0.f, 0.f};

#pragma unroll
    for (int kc = 0; kc < 4; ++kc) {
        int bc = (kc * 4 + lg) ^ (xrow & 7);
        bf16x8 bfrag = *reinterpret_cast<const bf16x8*>(xg + bc * 8);
        const unsigned short* wp = Wt + (size_t)l15 * HID + kc * 32 + lg * 8;
        bf16x8 af[8];
#pragma unroll
        for (int t = 0; t < 8; ++t) af[t] = *reinterpret_cast<const bf16x8*>(wp + (size_t)t * 16 * HID);
#pragma unroll
        for (int t = 0; t < 8; ++t)
            acc[t] = __builtin_amdgcn_mfma_f32_16x16x32_bf16(af[t], bfrag, acc[t], 0, 0, 0);
    }

    float s = 0.f, q = 0.f;
#pragma unroll
    for (int t = 0; t < 8; ++t) {
        int c0 = t * 16 + lg * 4;
        f32x4 bb = *reinterpret_cast<const f32x4*>(bias + c0);
        acc[t] = acc[t] + bb;
        s += acc[t].x + acc[t].y + acc[t].z + acc[t].w;
        q += acc[t].x * acc[t].x + acc[t].y * acc[t].y + acc[t].z * acc[t].z + acc[t].w * acc[t].w;
    }
    s += __shfl_xor(s, 16, 64);
    s += __shfl_xor(s, 32, 64);
    q += __shfl_xor(q, 16, 64);
    q += __shfl_xor(q, 32, 64);
    float mu = s * (1.0f / HID);
    float var = q * (1.0f / HID) - mu * mu;
    float rs = rsqrtf(var + LN_EPS);

    if (grow < n) {
#pragma unroll
        for (int t = 0; t < 8; ++t) {
            int c0 = t * 16 + lg * 4;
            uint2 rv = *reinterpret_cast<const uint2*>(hin + (size_t)grow * 64 + t * 8 + lg * 2);
            f32x4 gv = *reinterpret_cast<const f32x4*>(g + c0);
            f32x4 lb = *reinterpret_cast<const f32x4*>(lnb + c0);
            float o0 = fmaxf((acc[t].x - mu) * rs * gv.x + lb.x, 0.f) + bflo(rv.x);
            float o1 = fmaxf((acc[t].y - mu) * rs * gv.y + lb.y, 0.f) + bfhi(rv.x);
            float o2 = fmaxf((acc[t].z - mu) * rs * gv.z + lb.z, 0.f) + bflo(rv.y);
            float o3 = fmaxf((acc[t].w - mu) * rs * gv.w + lb.w, 0.f) + bfhi(rv.y);
            uint2 p;
            p.x = f2bf(o0) | (f2bf(o1) << 16);
            p.y = f2bf(o2) | (f2bf(o3) << 16);
            *reinterpret_cast<uint2*>(hout + (size_t)grow * 64 + t * 8 + lg * 2) = p;
        }
    }
}

// ---------------- FINAL layer: same as k_layer but fuses the masked column-sum; no hout write ----------------
__global__ __launch_bounds__(256) void k_layerF(const unsigned* __restrict__ hin,
                                                const unsigned* __restrict__ aggx,
                                                const unsigned short* __restrict__ Wt,
                                                const float* __restrict__ bias, const float* __restrict__ g,
                                                const float* __restrict__ lnb,
                                                const int* __restrict__ n_act_p,
                                                float* __restrict__ accum) {
    __shared__ float red[4][4][8][4];   // [wave][lg][t][j] = 2 KB
    const int tid = threadIdx.x;
    const int row0 = blockIdx.x * RT;
    const int lane = tid & 63;
    const int w = tid >> 6;
    const int l15 = lane & 15, lg = lane >> 4;
    const int xrow = w * 16 + l15;
    const int grow = row0 + xrow;
    const int na = *n_act_p;

    const unsigned short* xg = reinterpret_cast<const unsigned short*>(aggx) + (size_t)grow * HID;

    f32x4 acc[8];
#pragma unroll
    for (int t = 0; t < 8; ++t) acc[t] = (f32x4){0.f, 0.f, 0.f, 0.f};

#pragma unroll
    for (int kc = 0; kc < 4; ++kc) {
        int bc = (kc * 4 + lg) ^ (xrow & 7);
        bf16x8 bfrag = *reinterpret_cast<const bf16x8*>(xg + bc * 8);
        const unsigned short* wp = Wt + (size_t)l15 * HID + kc * 32 + lg * 8;
        bf16x8 af[8];
#pragma unroll
        for (int t = 0; t < 8; ++t) af[t] = *reinterpret_cast<const bf16x8*>(wp + (size_t)t * 16 * HID);
#pragma unroll
        for (int t = 0; t < 8; ++t)
            acc[t] = __builtin_amdgcn_mfma_f32_16x16x32_bf16(af[t], bfrag, acc[t], 0, 0, 0);
    }

    float s = 0.f, q = 0.f;
#pragma unroll
    for (int t = 0; t < 8; ++t) {
        int c0 = t * 16 + lg * 4;
        f32x4 bb = *reinterpret_cast<const f32x4*>(bias + c0);
        acc[t] = acc[t] + bb;
        s += acc[t].x + acc[t].y + acc[t].z + acc[t].w;
        q += acc[t].x * acc[t].x + acc[t].y * acc[t].y + acc[t].z * acc[t].z + acc[t].w * acc[t].w;
    }
    s += __shfl_xor(s, 16, 64);
    s += __shfl_xor(s, 32, 64);
    q += __shfl_xor(q, 16, 64);
    q += __shfl_xor(q, 32, 64);
    float mu = s * (1.0f / HID);
    float var = q * (1.0f / HID) - mu * mu;
    float rs = rsqrtf(var + LN_EPS);

    const float msk = (grow < na) ? 1.f : 0.f;   // rows >= na (incl. tail garbage) contribute 0
#pragma unroll
    for (int t = 0; t < 8; ++t) {
        int c0 = t * 16 + lg * 4;
        // residual read is in-bounds of the workspace even for tail rows; value masked below
        uint2 rv = *reinterpret_cast<const uint2*>(hin + (size_t)grow * 64 + t * 8 + lg * 2);
        f32x4 gv = *reinterpret_cast<const f32x4*>(g + c0);
        f32x4 lb = *reinterpret_cast<const f32x4*>(lnb + c0);
        float o0 = (fmaxf((acc[t].x - mu) * rs * gv.x + lb.x, 0.f) + bflo(rv.x)) * msk;
        float o1 = (fmaxf((acc[t].y - mu) * rs * gv.y + lb.y, 0.f) + bfhi(rv.x)) * msk;
        float o2 = (fmaxf((acc[t].z - mu) * rs * gv.z + lb.z, 0.f) + bflo(rv.y)) * msk;
        float o3 = (fmaxf((acc[t].w - mu) * rs * gv.w + lb.w, 0.f) + bfhi(rv.y)) * msk;
        // sum over the 16 rows covered by l15 lanes
#pragma unroll
        for (int m = 1; m < 16; m <<= 1) {
            o0 += __shfl_xor(o0, m, 64);
            o1 += __shfl_xor(o1, m, 64);
            o2 += __shfl_xor(o2, m, 64);
            o3 += __shfl_xor(o3, m, 64);
        }
        if (l15 == 0) {
            red[w][lg][t][0] = o0;
            red[w][lg][t][1] = o1;
            red[w][lg][t][2] = o2;
            red[w][lg][t][3] = o3;
        }
    }
    __syncthreads();
    if (tid < HID) {
        int t = tid >> 4, rem = tid & 15;
        int lgq = rem >> 2, j = rem & 3;
        float v = red[0][lgq][t][j] + red[1][lgq][t][j] + red[2][lgq][t][j] + red[3][lgq][t][j];
        atomicAdd(&accum[tid], v);
    }
}

__global__ void k_out(const float* __restrict__ accum, const int* __restrict__ n_act_p,
                      const float* __restrict__ W_out, const float* __restrict__ b_out,
                      float* __restrict__ out) {
    __shared__ float m[HID];
    int c = threadIdx.x;
    float na = (float)(*n_act_p);
    m[c] = accum[c] / na;
    __syncthreads();
    float s = b_out[c];
    for (int k = 0; k < HID; ++k) s += m[k] * W_out[k * HID + c];
    out[c] = s;
}

extern "C" void kernel_launch(void* const* d_in, const int* in_sizes, int n_in,
                              void* d_out, int out_size, void* d_ws, size_t ws_size,
                              hipStream_t stream) {
    const int n  = in_sizes[0] / INP;   // 50000
    const int nE = in_sizes[1] / 2;     // 800000
    const float* x    = (const float*)d_in[0];
    const int*   ei   = (const int*)d_in[1];
    const int*   src  = ei;
    const int*   dst  = ei + nE;
    const int*   nact = (const int*)d_in[2];
    const float* W_in = (const float*)d_in[3];
    const float* b_in = (const float*)d_in[4];
    const float* W_l  = (const float*)d_in[5];
    const float* b_l  = (const float*)d_in[6];
    const float* lng  = (const float*)d_in[7];
    const float* lnb  = (const float*)d_in[8];
    const float* W_o  = (const float*)d_in[9];
    const float* b_o  = (const float*)d_in[10];

    char* ws = (char*)d_ws;
    size_t off = 0;
    auto alloc = [&](size_t bytes) {
        void* p = ws + off;
        off = (off + bytes + 255) & ~((size_t)255);
        return p;
    };
    unsigned* hbA  = (unsigned*)alloc((size_t)n * 64 * 4);
    unsigned* hbB  = (unsigned*)alloc((size_t)n * 64 * 4);
    unsigned* aggx = (unsigned*)alloc((size_t)(n + RT) * 64 * 4);  // +RT rows pad for tail-block frag reads
    size_t cntBytes = (((size_t)n * 4) + 255) & ~((size_t)255);
    int*   cnt   = (int*)alloc(cntBytes);
    float* accum = (float*)alloc(HID * 4);   // adjacent to cnt -> one memset covers both
    int*   rowp = (int*)alloc((size_t)(n + 1) * 4);
    float* invd = (float*)alloc((size_t)n * 4);
    int*   csrc = (int*)alloc((size_t)nE * 4);
    int*   rank = (int*)alloc((size_t)nE * 4);
    int*   bsum = (int*)alloc(1024);
    unsigned short* Wt_in = (unsigned short*)alloc(128 * 64 * 2);
    unsigned short* Wt_l  = (unsigned short*)alloc(3 * 128 * 128 * 2);

    hipMemsetAsync(cnt, 0, cntBytes + HID * 4, stream);

    int nb = (n + 255) / 256;
    int nEdgeThreads = (nE + 15) / 16;                       // 16 edges/thread
    int nPrep = 128 * 64 + 3 * 128 * 128;
    int cpgrid = (nEdgeThreads + nPrep + 255) / 256;
    k_count<<<cpgrid, 256, 0, stream>>>(dst, nE, cnt, rank, nEdgeThreads, W_in, W_l, Wt_in, Wt_l);
    k_scan1<<<nb, 256, 0, stream>>>(cnt, n, rowp, bsum);
    k_scan3<<<nb, 256, 0, stream>>>(rowp, bsum, cnt, n, nE, invd, nb);

    int tgrid = (n + RT - 1) / RT;
    int fgrid = (nEdgeThreads + 255) / 256;
    k_fillproj<<<tgrid + fgrid, 256, 0, stream>>>(x, Wt_in, b_in, hbA, n, tgrid,
                                                  src, dst, rank, rowp, nE, csrc);

    const unsigned* hin = hbA;
    unsigned* hout = hbB;
    for (int l = 0; l < 3; ++l) {
        k_agg<<<(n + 3) / 4, 256, 0, stream>>>(hin, rowp, csrc, invd, aggx, n);
        if (l < 2) {
            k_layer<<<tgrid, 256, 0, stream>>>(hin, hout, aggx,
                                               Wt_l + (size_t)l * 128 * 128,
                                               b_l + l * HID, lng + l * HID, lnb + l * HID, n);
            const unsigned* t = hout;
            hout = (unsigned*)hin;
            hin = t;
        } else {
            k_layerF<<<tgrid, 256, 0, stream>>>(hin, aggx,
                                                Wt_l + (size_t)l * 128 * 128,
                                                b_l + l * HID, lng + l * HID, lnb + l * HID,
                                                nact, accum);
        }
    }
    k_out<<<1, HID, 0, stream>>>(accum, nact, W_o, b_o, (float*)d_out);
}